// Round 1
// baseline (257.651 us; speedup 1.0000x reference)
//
#include <hip/hip_runtime.h>
#include <math.h>

#define B_ 256
#define I_ 512
#define H_ 512
#define BH (B_*H_)
#define NCH 8            // h-chunks for hebbdot partials
#define HCH (H_/NCH)     // 64

// ws layout (floats):
// [0, 4*BH)        : gate pre-acts pf,pi,po,pc   (4 * 131072)
// [4*BH, 12*BH)    : hebbdot partials [NCH][B][H]
// [12*BH, 13*BH)   : v[b,k] = (myeta*Wfan[k]+bfan[k])*c2[b,k]
// total 13*BH*4 = 6.8 MB

// ---------------------------------------------------------------------------
// K1: hebbdot partials: part[ch][b][k] = sum_{h in chunk} h0[b,h]*hebb[b,h,k]
// ---------------------------------------------------------------------------
__global__ __launch_bounds__(128) void k_hebbdot(const float* __restrict__ hebb,
                                                 const float* __restrict__ h0,
                                                 float* __restrict__ part) {
    int b  = blockIdx.x;   // 0..255
    int ch = blockIdx.y;   // 0..7
    int t  = threadIdx.x;  // 0..127, one float4 of k each (128*4 = 512)

    __shared__ float h0s[HCH];
    if (t < HCH) h0s[t] = h0[b * H_ + ch * HCH + t];
    __syncthreads();

    const float4* hb = (const float4*)(hebb + ((size_t)b * H_ + (size_t)ch * HCH) * H_);
    float4 acc = make_float4(0.f, 0.f, 0.f, 0.f);
    #pragma unroll 8
    for (int hh = 0; hh < HCH; ++hh) {
        float s = h0s[hh];
        float4 v = hb[hh * (H_ / 4) + t];
        acc.x += s * v.x; acc.y += s * v.y; acc.z += s * v.z; acc.w += s * v.w;
    }
    float4* pout = (float4*)(part + ((size_t)ch * B_ + b) * H_);
    pout[t] = acc;
}

// ---------------------------------------------------------------------------
// K2: fused gate GEMM.  Virtual C[m, n], m=b in [0,256), n in [0,2048):
//   g = n>>9 (0=f,1=i,2=o,3=c), ko = n&511
//   g<3 : C = inputs@Wxg.T + h0@Whg.T  (+ bx+bh in epilogue)
//   g==3: C = inputs@Wxc.T + h0@w      (+ bxc)        [w NOT transposed]
// K = 1024 (first 512 = inputs vs Wx, last 512 = h0 vs Wh/w)
// ---------------------------------------------------------------------------
#define TM 64
#define TN 64
#define TK 16

__global__ __launch_bounds__(256) void k_gates(
    const float* __restrict__ inputs, const float* __restrict__ h0,
    const float* __restrict__ Wxf, const float* __restrict__ bxf,
    const float* __restrict__ Whf, const float* __restrict__ bhf,
    const float* __restrict__ Wxi, const float* __restrict__ bxi,
    const float* __restrict__ Whi, const float* __restrict__ bhi,
    const float* __restrict__ Wxo, const float* __restrict__ bxo,
    const float* __restrict__ Who, const float* __restrict__ bho,
    const float* __restrict__ Wxc, const float* __restrict__ bxc,
    const float* __restrict__ w,
    float* __restrict__ pre) {

    int n0 = blockIdx.x * TN;     // [0,2048)
    int m0 = blockIdx.y * TM;     // [0,256)
    int g  = n0 >> 9;             // uniform per block (512 % TN == 0)
    int ko0 = n0 & 511;

    const float* Wx; const float* Wh;
    if (g == 0)      { Wx = Wxf; Wh = Whf; }
    else if (g == 1) { Wx = Wxi; Wh = Whi; }
    else if (g == 2) { Wx = Wxo; Wh = Who; }
    else             { Wx = Wxc; Wh = w;   }

    __shared__ float As[TK][TM + 1];
    __shared__ float Bs[TK][TN + 1];

    int tid = threadIdx.x;
    int tx = tid & 15, ty = tid >> 4;

    float acc[4][4];
    #pragma unroll
    for (int i = 0; i < 4; ++i)
        #pragma unroll
        for (int j = 0; j < 4; ++j) acc[i][j] = 0.f;

    for (int k0 = 0; k0 < 1024; k0 += TK) {
        const float* Ab = (k0 < 512) ? inputs : h0;
        int kbase = k0 & 511;
        // --- load A tile: As[kk][m] ---
        {
            int lk = tid & 15;        // kk
            int lm = tid >> 4;        // m (16 per pass)
            #pragma unroll
            for (int p = 0; p < 4; ++p)
                As[lk][lm + 16 * p] = Ab[(size_t)(m0 + lm + 16 * p) * 512 + kbase + lk];
        }
        // --- load B tile: Bs[kk][n] ---
        if (g == 3 && k0 >= 512) {
            // w path: w[h, ko] — contiguous in n
            int kk  = tid >> 4;
            int ln0 = tid & 15;
            #pragma unroll
            for (int p = 0; p < 4; ++p)
                Bs[kk][ln0 + 16 * p] = w[(size_t)(kbase + kk) * 512 + ko0 + ln0 + 16 * p];
        } else {
            const float* Wm = (k0 < 512) ? Wx : Wh;   // row-major [ko][kidx]
            int lk = tid & 15;
            int ln = tid >> 4;
            #pragma unroll
            for (int p = 0; p < 4; ++p)
                Bs[lk][ln + 16 * p] = Wm[(size_t)(ko0 + ln + 16 * p) * 512 + kbase + lk];
        }
        __syncthreads();
        #pragma unroll
        for (int kk = 0; kk < TK; ++kk) {
            float a[4], bb[4];
            #pragma unroll
            for (int i = 0; i < 4; ++i) a[i]  = As[kk][ty * 4 + i];
            #pragma unroll
            for (int j = 0; j < 4; ++j) bb[j] = Bs[kk][tx * 4 + j];
            #pragma unroll
            for (int i = 0; i < 4; ++i)
                #pragma unroll
                for (int j = 0; j < 4; ++j) acc[i][j] += a[i] * bb[j];
        }
        __syncthreads();
    }

    // epilogue: add biases, write pre[g*BH + b*H + ko]
    #pragma unroll
    for (int j = 0; j < 4; ++j) {
        int ko = ko0 + tx * 4 + j;
        float bias;
        if (g == 0)      bias = bxf[ko] + bhf[ko];
        else if (g == 1) bias = bxi[ko] + bhi[ko];
        else if (g == 2) bias = bxo[ko] + bho[ko];
        else             bias = bxc[ko];
        #pragma unroll
        for (int i = 0; i < 4; ++i) {
            int bnum = m0 + ty * 4 + i;
            pre[(size_t)g * BH + (size_t)bnum * H_ + ko] = acc[i][j] + bias;
        }
    }
}

// ---------------------------------------------------------------------------
// K3: finalize per sample: activations, hactiv/cell outputs, myeta, v
// ---------------------------------------------------------------------------
__global__ __launch_bounds__(256) void k_finalize(
    const float* __restrict__ pre, const float* __restrict__ part,
    const float* __restrict__ c0, const float* __restrict__ alpha,
    const float* __restrict__ Wmod, const float* __restrict__ bmod,
    const float* __restrict__ Wfan, const float* __restrict__ bfan,
    float* __restrict__ out, float* __restrict__ v) {

    int b = blockIdx.x;
    int t = threadIdx.x;

    float c2r[2];
    float local = 0.f;
    #pragma unroll
    for (int s = 0; s < 2; ++s) {
        int k = t + s * 256;
        float dot = 0.f;
        #pragma unroll
        for (int c = 0; c < NCH; ++c) dot += part[((size_t)c * B_ + b) * H_ + k];
        float pf = pre[0 * BH + (size_t)b * H_ + k];
        float pi = pre[1 * BH + (size_t)b * H_ + k];
        float po = pre[2 * BH + (size_t)b * H_ + k];
        float pc = pre[3 * BH + (size_t)b * H_ + k];
        float c2 = tanhf(pc + alpha[k] * dot);
        float fg = 1.f / (1.f + expf(-pf));
        float ig = 1.f / (1.f + expf(-pi));
        float og = 1.f / (1.f + expf(-po));
        float cell = fg * c0[(size_t)b * H_ + k] + ig * c2;
        float ha = og * tanhf(cell);
        out[(size_t)b * H_ + k] = ha;           // hactiv
        out[BH + (size_t)b * H_ + k] = cell;    // cell
        c2r[s] = c2;
        local += ha * Wmod[k];
    }
    // block reduction (4 waves of 64)
    float x = local;
    #pragma unroll
    for (int off = 32; off > 0; off >>= 1) x += __shfl_down(x, off, 64);
    __shared__ float red[4];
    int wid = t >> 6, lane = t & 63;
    if (lane == 0) red[wid] = x;
    __syncthreads();
    float s4 = red[0] + red[1] + red[2] + red[3];
    float myeta = tanhf(s4 + bmod[0]);
    #pragma unroll
    for (int s = 0; s < 2; ++s) {
        int k = t + s * 256;
        v[(size_t)b * H_ + k] = (myeta * Wfan[k] + bfan[k]) * c2r[s];
    }
}

// ---------------------------------------------------------------------------
// K4: hebb_new[b,h,k] = clip(hebb + h0[b,h]*v[b,k], -2, 2)   (pure stream)
// ---------------------------------------------------------------------------
__global__ __launch_bounds__(256) void k_update(
    const float4* __restrict__ hebb, const float* __restrict__ h0,
    const float4* __restrict__ v, float4* __restrict__ out) {
    const int total = B_ * H_ * (H_ / 4);   // 16,777,216 float4
    int stride = gridDim.x * blockDim.x;
    for (int f = blockIdx.x * blockDim.x + threadIdx.x; f < total; f += stride) {
        int k4 = f & 127;           // float4 col
        int h  = (f >> 7) & 511;
        int b  = f >> 16;
        float u = h0[(b << 9) + h];
        float4 vv = v[(b << 7) + k4];
        float4 hb = hebb[f];
        float4 r;
        r.x = fminf(fmaxf(hb.x + u * vv.x, -2.f), 2.f);
        r.y = fminf(fmaxf(hb.y + u * vv.y, -2.f), 2.f);
        r.z = fminf(fmaxf(hb.z + u * vv.z, -2.f), 2.f);
        r.w = fminf(fmaxf(hb.w + u * vv.w, -2.f), 2.f);
        out[f] = r;
    }
}

// ---------------------------------------------------------------------------
extern "C" void kernel_launch(void* const* d_in, const int* in_sizes, int n_in,
                              void* d_out, int out_size, void* d_ws, size_t ws_size,
                              hipStream_t stream) {
    const float* inputs = (const float*)d_in[0];
    const float* h0     = (const float*)d_in[1];
    const float* c0     = (const float*)d_in[2];
    const float* hebb   = (const float*)d_in[3];
    const float* w      = (const float*)d_in[4];
    const float* alpha  = (const float*)d_in[5];
    const float* Wxf = (const float*)d_in[6];  const float* bxf = (const float*)d_in[7];
    const float* Whf = (const float*)d_in[8];  const float* bhf = (const float*)d_in[9];
    const float* Wxi = (const float*)d_in[10]; const float* bxi = (const float*)d_in[11];
    const float* Whi = (const float*)d_in[12]; const float* bhi = (const float*)d_in[13];
    const float* Wxo = (const float*)d_in[14]; const float* bxo = (const float*)d_in[15];
    const float* Who = (const float*)d_in[16]; const float* bho = (const float*)d_in[17];
    const float* Wxc = (const float*)d_in[18]; const float* bxc = (const float*)d_in[19];
    const float* Wmod = (const float*)d_in[20]; const float* bmod = (const float*)d_in[21];
    const float* Wfan = (const float*)d_in[22]; const float* bfan = (const float*)d_in[23];

    float* out = (float*)d_out;
    float* ws  = (float*)d_ws;
    float* pre  = ws;                 // 4*BH
    float* part = ws + 4 * BH;        // 8*BH
    float* vbuf = ws + 12 * BH;       // BH

    // K1: hebbdot partials (268 MB stream)
    k_hebbdot<<<dim3(B_, NCH), 128, 0, stream>>>(hebb, h0, part);
    // K2: fused gate GEMM
    k_gates<<<dim3(2048 / TN, B_ / TM), 256, 0, stream>>>(
        inputs, h0, Wxf, bxf, Whf, bhf, Wxi, bxi, Whi, bhi,
        Wxo, bxo, Who, bho, Wxc, bxc, w, pre);
    // K3: finalize
    k_finalize<<<B_, 256, 0, stream>>>(pre, part, c0, alpha, Wmod, bmod,
                                       Wfan, bfan, out, vbuf);
    // K4: hebb update (537 MB stream)
    k_update<<<2048, 256, 0, stream>>>((const float4*)hebb, h0,
                                       (const float4*)vbuf,
                                       (float4*)(out + 2 * BH));
}

// Round 2
// 214.010 us; speedup vs baseline: 1.2039x; 1.2039x over previous
//
#include <hip/hip_runtime.h>
#include <math.h>

#define B_ 256
#define I_ 512
#define H_ 512
#define BH (B_*H_)
#define NCH 8            // h-chunks for hebbdot partials
#define HCH (H_/NCH)     // 64

typedef float f4v __attribute__((ext_vector_type(4)));

// ws layout (floats):
// [0, 4*BH)        : gate pre-acts pf,pi,po,pc   (4 * 131072)
// [4*BH, 12*BH)    : hebbdot partials [NCH][B][H]
// [12*BH, 13*BH)   : v[b,k] = (myeta*Wfan[k]+bfan[k])*c2[b,k]

// ---------------------------------------------------------------------------
// Fused K1+K2: blocks [0,128) do the gate GEMM, blocks [128, 128+2048) do
// hebbdot partials. GEMM is compute-bound, hebbdot is HBM-bound -> overlap.
// ---------------------------------------------------------------------------
#define TM 64
#define TN 64
#define TK 16
#define LDT 68           // padded LDS row stride (68*4 B, 16B-aligned)
#define NGEMM 128        // (2048/TN)*(256/TM)

__global__ __launch_bounds__(256) void k_dot_gates(
    const float* __restrict__ hebb, const float* __restrict__ h0,
    const float* __restrict__ inputs,
    const float* __restrict__ Wxf, const float* __restrict__ bxf,
    const float* __restrict__ Whf, const float* __restrict__ bhf,
    const float* __restrict__ Wxi, const float* __restrict__ bxi,
    const float* __restrict__ Whi, const float* __restrict__ bhi,
    const float* __restrict__ Wxo, const float* __restrict__ bxo,
    const float* __restrict__ Who, const float* __restrict__ bho,
    const float* __restrict__ Wxc, const float* __restrict__ bxc,
    const float* __restrict__ w,
    float* __restrict__ pre, float* __restrict__ part) {

    __shared__ float smem[2 * TK * LDT];   // 8704 B, aliased by both paths
    int bid = blockIdx.x;
    int tid = threadIdx.x;

    if (bid < NGEMM) {
        // ---------------- gate GEMM path ----------------
        int n0 = (bid & 31) * TN;     // [0,2048)
        int m0 = (bid >> 5) * TM;     // [0,256)
        int g  = n0 >> 9;             // 0=f,1=i,2=o,3=c (uniform per block)
        int ko0 = n0 & 511;

        const float* Wx; const float* Wh;
        if (g == 0)      { Wx = Wxf; Wh = Whf; }
        else if (g == 1) { Wx = Wxi; Wh = Whi; }
        else if (g == 2) { Wx = Wxo; Wh = Who; }
        else             { Wx = Wxc; Wh = w;   }

        float* As = smem;              // [TK][LDT]
        float* Bs = smem + TK * LDT;   // [TK][LDT]
        int tx = tid & 15, ty = tid >> 4;

        float acc[4][4];
        #pragma unroll
        for (int i = 0; i < 4; ++i)
            #pragma unroll
            for (int j = 0; j < 4; ++j) acc[i][j] = 0.f;

        for (int k0 = 0; k0 < 1024; k0 += TK) {
            const float* Ab = (k0 < 512) ? inputs : h0;
            int kbase = k0 & 511;
            {   // A tile: As[kk][m]
                int lk = tid & 15, lm = tid >> 4;
                #pragma unroll
                for (int p = 0; p < 4; ++p)
                    As[lk * LDT + lm + 16 * p] =
                        Ab[(size_t)(m0 + lm + 16 * p) * 512 + kbase + lk];
            }
            if (g == 3 && k0 >= 512) {
                // w path: w[h, ko] — contiguous in n
                int kk = tid >> 4, ln0 = tid & 15;
                #pragma unroll
                for (int p = 0; p < 4; ++p)
                    Bs[kk * LDT + ln0 + 16 * p] =
                        w[(size_t)(kbase + kk) * 512 + ko0 + ln0 + 16 * p];
            } else {
                const float* Wm = (k0 < 512) ? Wx : Wh;  // [ko][kidx] row-major
                int lk = tid & 15, ln = tid >> 4;
                #pragma unroll
                for (int p = 0; p < 4; ++p)
                    Bs[lk * LDT + ln + 16 * p] =
                        Wm[(size_t)(ko0 + ln + 16 * p) * 512 + kbase + lk];
            }
            __syncthreads();
            #pragma unroll
            for (int kk = 0; kk < TK; ++kk) {
                float4 a4 = *(const float4*)&As[kk * LDT + ty * 4];
                float4 b4 = *(const float4*)&Bs[kk * LDT + tx * 4];
                float a[4] = {a4.x, a4.y, a4.z, a4.w};
                float bb[4] = {b4.x, b4.y, b4.z, b4.w};
                #pragma unroll
                for (int i = 0; i < 4; ++i)
                    #pragma unroll
                    for (int j = 0; j < 4; ++j) acc[i][j] += a[i] * bb[j];
            }
            __syncthreads();
        }
        #pragma unroll
        for (int j = 0; j < 4; ++j) {
            int ko = ko0 + tx * 4 + j;
            float bias;
            if (g == 0)      bias = bxf[ko] + bhf[ko];
            else if (g == 1) bias = bxi[ko] + bhi[ko];
            else if (g == 2) bias = bxo[ko] + bho[ko];
            else             bias = bxc[ko];
            #pragma unroll
            for (int i = 0; i < 4; ++i) {
                int bnum = m0 + ty * 4 + i;
                pre[(size_t)g * BH + (size_t)bnum * H_ + ko] = acc[i][j] + bias;
            }
        }
    } else {
        // ---------------- hebbdot path ----------------
        int hbid = bid - NGEMM;
        int b  = hbid >> 3;    // consecutive blocks share b -> L2 locality
        int ch = hbid & 7;

        float*  h0s = smem;                    // [64]
        float4* red = (float4*)(smem + 64);    // [256]

        if (tid < HCH) h0s[tid] = h0[b * H_ + ch * HCH + tid];
        __syncthreads();

        const float4* hbp = (const float4*)(hebb + ((size_t)b * H_ + (size_t)ch * HCH) * H_);
        int tk = tid & 127;    // float4 column
        int th = tid >> 7;     // 0,1 — split h range
        float4 acc = make_float4(0.f, 0.f, 0.f, 0.f);
        #pragma unroll 8
        for (int r = 0; r < 32; ++r) {
            int hh = th * 32 + r;
            float s = h0s[hh];
            float4 vv = hbp[(size_t)hh * 128 + tk];
            acc.x += s * vv.x; acc.y += s * vv.y;
            acc.z += s * vv.z; acc.w += s * vv.w;
        }
        red[tid] = acc;
        __syncthreads();
        if (tid < 128) {
            float4 a = red[tid], c = red[tid + 128];
            float4 o = make_float4(a.x + c.x, a.y + c.y, a.z + c.z, a.w + c.w);
            ((float4*)(part + ((size_t)ch * B_ + b) * H_))[tid] = o;
        }
    }
}

// ---------------------------------------------------------------------------
// K3: finalize per sample: activations, hactiv/cell outputs, myeta, v
// ---------------------------------------------------------------------------
__global__ __launch_bounds__(256) void k_finalize(
    const float* __restrict__ pre, const float* __restrict__ part,
    const float* __restrict__ c0, const float* __restrict__ alpha,
    const float* __restrict__ Wmod, const float* __restrict__ bmod,
    const float* __restrict__ Wfan, const float* __restrict__ bfan,
    float* __restrict__ out, float* __restrict__ v) {

    int b = blockIdx.x;
    int t = threadIdx.x;

    float c2r[2];
    float local = 0.f;
    #pragma unroll
    for (int s = 0; s < 2; ++s) {
        int k = t + s * 256;
        float dot = 0.f;
        #pragma unroll
        for (int c = 0; c < NCH; ++c) dot += part[((size_t)c * B_ + b) * H_ + k];
        float pf = pre[0 * BH + (size_t)b * H_ + k];
        float pi = pre[1 * BH + (size_t)b * H_ + k];
        float po = pre[2 * BH + (size_t)b * H_ + k];
        float pc = pre[3 * BH + (size_t)b * H_ + k];
        float c2 = tanhf(pc + alpha[k] * dot);
        float fg = 1.f / (1.f + expf(-pf));
        float ig = 1.f / (1.f + expf(-pi));
        float og = 1.f / (1.f + expf(-po));
        float cell = fg * c0[(size_t)b * H_ + k] + ig * c2;
        float ha = og * tanhf(cell);
        out[(size_t)b * H_ + k] = ha;           // hactiv
        out[BH + (size_t)b * H_ + k] = cell;    // cell
        c2r[s] = c2;
        local += ha * Wmod[k];
    }
    float x = local;
    #pragma unroll
    for (int off = 32; off > 0; off >>= 1) x += __shfl_down(x, off, 64);
    __shared__ float red[4];
    int wid = t >> 6, lane = t & 63;
    if (lane == 0) red[wid] = x;
    __syncthreads();
    float s4 = red[0] + red[1] + red[2] + red[3];
    float myeta = tanhf(s4 + bmod[0]);
    #pragma unroll
    for (int s = 0; s < 2; ++s) {
        int k = t + s * 256;
        v[(size_t)b * H_ + k] = (myeta * Wfan[k] + bfan[k]) * c2r[s];
    }
}

// ---------------------------------------------------------------------------
// K4: hebb_new[b,h,k] = clip(hebb + h0[b,h]*v[b,k], -2, 2)
// Reverse-order stream (tail of K1's read is freshest in L3) + NT stores so
// the write stream doesn't evict cached hebb.
// ---------------------------------------------------------------------------
__global__ __launch_bounds__(256) void k_update(
    const float4* __restrict__ hebb, const float* __restrict__ h0,
    const float* __restrict__ v, float* __restrict__ out) {
    const int total = B_ * H_ * (H_ / 4);   // 16,777,216 float4
    int stride = gridDim.x * blockDim.x;    // 524,288
    int base = blockIdx.x * blockDim.x + threadIdx.x;
    for (int f = total - stride + base; f >= 0; f -= stride) {
        int k4 = f & 127;           // float4 col
        int h  = (f >> 7) & 511;
        int b  = f >> 16;
        float u = h0[(b << 9) + h];
        const float4* vv4 = (const float4*)v;
        float4 vv = vv4[(b << 7) + k4];
        float4 hb = hebb[f];
        f4v r;
        r.x = fminf(fmaxf(hb.x + u * vv.x, -2.f), 2.f);
        r.y = fminf(fmaxf(hb.y + u * vv.y, -2.f), 2.f);
        r.z = fminf(fmaxf(hb.z + u * vv.z, -2.f), 2.f);
        r.w = fminf(fmaxf(hb.w + u * vv.w, -2.f), 2.f);
        __builtin_nontemporal_store(r, (f4v*)(out) + f);
    }
}

// ---------------------------------------------------------------------------
extern "C" void kernel_launch(void* const* d_in, const int* in_sizes, int n_in,
                              void* d_out, int out_size, void* d_ws, size_t ws_size,
                              hipStream_t stream) {
    const float* inputs = (const float*)d_in[0];
    const float* h0     = (const float*)d_in[1];
    const float* c0     = (const float*)d_in[2];
    const float* hebb   = (const float*)d_in[3];
    const float* w      = (const float*)d_in[4];
    const float* alpha  = (const float*)d_in[5];
    const float* Wxf = (const float*)d_in[6];  const float* bxf = (const float*)d_in[7];
    const float* Whf = (const float*)d_in[8];  const float* bhf = (const float*)d_in[9];
    const float* Wxi = (const float*)d_in[10]; const float* bxi = (const float*)d_in[11];
    const float* Whi = (const float*)d_in[12]; const float* bhi = (const float*)d_in[13];
    const float* Wxo = (const float*)d_in[14]; const float* bxo = (const float*)d_in[15];
    const float* Who = (const float*)d_in[16]; const float* bho = (const float*)d_in[17];
    const float* Wxc = (const float*)d_in[18]; const float* bxc = (const float*)d_in[19];
    const float* Wmod = (const float*)d_in[20]; const float* bmod = (const float*)d_in[21];
    const float* Wfan = (const float*)d_in[22]; const float* bfan = (const float*)d_in[23];

    float* out = (float*)d_out;
    float* ws  = (float*)d_ws;
    float* pre  = ws;                 // 4*BH
    float* part = ws + 4 * BH;        // 8*BH
    float* vbuf = ws + 12 * BH;       // BH

    // Fused: gate GEMM (128 blocks, dispatched first) + hebbdot (2048 blocks)
    k_dot_gates<<<NGEMM + B_ * NCH, 256, 0, stream>>>(
        hebb, h0, inputs,
        Wxf, bxf, Whf, bhf, Wxi, bxi, Whi, bhi,
        Wxo, bxo, Who, bho, Wxc, bxc, w, pre, part);
    // Finalize
    k_finalize<<<B_, 256, 0, stream>>>(pre, part, c0, alpha, Wmod, bmod,
                                       Wfan, bfan, out, vbuf);
    // Hebb update (reverse stream + NT stores)
    k_update<<<2048, 256, 0, stream>>>((const float4*)hebb, h0, vbuf,
                                       out + 2 * BH);
}

// Round 4
// 178.547 us; speedup vs baseline: 1.4430x; 1.1986x over previous
//
#include <hip/hip_runtime.h>
#include <math.h>

#define B_ 256
#define I_ 512
#define H_ 512
#define BH (B_*H_)
#define NCH 8            // h-chunks for hebbdot partials
#define HCH (H_/NCH)     // 64

typedef float f4v __attribute__((ext_vector_type(4)));

// ws layout (floats):
// [0, 4*BH)        : gate pre-acts pf,pi,po,pc
// [4*BH, 12*BH)    : hebbdot partials [NCH][B][H]
// [12*BH, 13*BH)   : v[b,k]

// ---------------------------------------------------------------------------
// Fused: blocks [0,512) gate GEMM (TM=TN=32, reg-prefetch + LDS dbuf),
// blocks [512, 512+2048) hebbdot partials (HBM-bound stream). Overlap.
// ---------------------------------------------------------------------------
#define TK 16
#define LDT2 34          // padded LDS row stride (floats); 34*4B, 8B-aligned
#define TILE_F (TK*LDT2) // 544 floats per tile buffer
#define NGEMM 512

__global__ __launch_bounds__(256) void k_dot_gates(
    const float* __restrict__ hebb, const float* __restrict__ h0,
    const float* __restrict__ inputs,
    const float* __restrict__ Wxf, const float* __restrict__ bxf,
    const float* __restrict__ Whf, const float* __restrict__ bhf,
    const float* __restrict__ Wxi, const float* __restrict__ bxi,
    const float* __restrict__ Whi, const float* __restrict__ bhi,
    const float* __restrict__ Wxo, const float* __restrict__ bxo,
    const float* __restrict__ Who, const float* __restrict__ bho,
    const float* __restrict__ Wxc, const float* __restrict__ bxc,
    const float* __restrict__ w,
    float* __restrict__ pre, float* __restrict__ part) {

    __shared__ float smem[4 * TILE_F];   // 8704 B; aliased by both paths
    int bid = blockIdx.x;
    int tid = threadIdx.x;

    if (bid < NGEMM) {
        // ---------------- gate GEMM path ----------------
        // 64 n-tiles x 8 m-tiles; same-n blocks adjacent (weight L2 reuse)
        int n0  = (bid >> 3) * 32;    // [0,2048)
        int m0  = (bid & 7) * 32;     // [0,256)
        int g   = n0 >> 9;            // 0=f,1=i,2=o,3=c (uniform)
        int ko0 = n0 & 511;

        const float* Wx; const float* Wh;
        if (g == 0)      { Wx = Wxf; Wh = Whf; }
        else if (g == 1) { Wx = Wxi; Wh = Whi; }
        else if (g == 2) { Wx = Wxo; Wh = Who; }
        else             { Wx = Wxc; Wh = w;   }

        int tx = tid & 15, ty = tid >> 4;
        int lk = tid & 15, lm = tid >> 4;   // A-load coords (k, m)
        int kk2 = tid >> 4, ln0 = tid & 15; // w-path B-load coords (k, n)

        float acc[2][2] = {{0.f, 0.f}, {0.f, 0.f}};
        float ar[2], br[2];

        // buffer layout: [A0 | B0 | A1 | B1], base offset pb*2*TILE_F
        auto LOAD = [&](int t) {
            int k0 = t * TK;
            const float* Ab = (k0 < 512) ? inputs : h0;
            int kbase = k0 & 511;
            #pragma unroll
            for (int p = 0; p < 2; ++p)
                ar[p] = Ab[(size_t)(m0 + lm + 16 * p) * 512 + kbase + lk];
            if (g == 3 && k0 >= 512) {
                #pragma unroll
                for (int p = 0; p < 2; ++p)
                    br[p] = w[(size_t)(kbase + kk2) * 512 + ko0 + ln0 + 16 * p];
            } else {
                const float* Wm = (k0 < 512) ? Wx : Wh;  // [ko][k] row-major
                #pragma unroll
                for (int p = 0; p < 2; ++p)
                    br[p] = Wm[(size_t)(ko0 + lm + 16 * p) * 512 + kbase + lk];
            }
        };
        auto STORE = [&](int t, int pbuf) {
            float* Asb = smem + pbuf * 2 * TILE_F;
            float* Bsb = Asb + TILE_F;
            int k0 = t * TK;
            #pragma unroll
            for (int p = 0; p < 2; ++p)
                Asb[lk * LDT2 + lm + 16 * p] = ar[p];
            if (g == 3 && k0 >= 512) {
                #pragma unroll
                for (int p = 0; p < 2; ++p)
                    Bsb[kk2 * LDT2 + ln0 + 16 * p] = br[p];
            } else {
                #pragma unroll
                for (int p = 0; p < 2; ++p)
                    Bsb[lk * LDT2 + lm + 16 * p] = br[p];
            }
        };

        LOAD(0);
        STORE(0, 0);
        for (int t = 0; t < 64; ++t) {
            __syncthreads();               // buf t&1 ready for all
            if (t < 63) LOAD(t + 1);
            int pb = t & 1;
            const float* Asb = smem + pb * 2 * TILE_F;
            const float* Bsb = Asb + TILE_F;
            #pragma unroll
            for (int kk = 0; kk < TK; ++kk) {
                float2 a2 = *(const float2*)&Asb[kk * LDT2 + ty * 2];
                float2 b2 = *(const float2*)&Bsb[kk * LDT2 + tx * 2];
                acc[0][0] += a2.x * b2.x; acc[0][1] += a2.x * b2.y;
                acc[1][0] += a2.y * b2.x; acc[1][1] += a2.y * b2.y;
            }
            if (t < 63) STORE(t + 1, pb ^ 1);
        }

        #pragma unroll
        for (int j = 0; j < 2; ++j) {
            int ko = ko0 + tx * 2 + j;
            float bias;
            if (g == 0)      bias = bxf[ko] + bhf[ko];
            else if (g == 1) bias = bxi[ko] + bhi[ko];
            else if (g == 2) bias = bxo[ko] + bho[ko];
            else             bias = bxc[ko];
            #pragma unroll
            for (int i = 0; i < 2; ++i) {
                int bnum = m0 + ty * 2 + i;
                pre[(size_t)g * BH + (size_t)bnum * H_ + ko] = acc[i][j] + bias;
            }
        }
    } else {
        // ---------------- hebbdot path ----------------
        int hbid = bid - NGEMM;
        int b  = hbid >> 3;    // consecutive blocks share b -> L2 locality
        int ch = hbid & 7;

        float*  h0s = smem;                    // [64]
        float4* red = (float4*)(smem + 64);    // [256]

        if (tid < HCH) h0s[tid] = h0[b * H_ + ch * HCH + tid];
        __syncthreads();

        const float4* hbp = (const float4*)(hebb + ((size_t)b * H_ + (size_t)ch * HCH) * H_);
        int tk = tid & 127;    // float4 column
        int th = tid >> 7;     // 0,1 — split h range
        float4 acc = make_float4(0.f, 0.f, 0.f, 0.f);
        #pragma unroll 8
        for (int r = 0; r < 32; ++r) {
            int hh = th * 32 + r;
            float s = h0s[hh];
            float4 vv = hbp[(size_t)hh * 128 + tk];
            acc.x += s * vv.x; acc.y += s * vv.y;
            acc.z += s * vv.z; acc.w += s * vv.w;
        }
        red[tid] = acc;
        __syncthreads();
        if (tid < 128) {
            float4 a = red[tid], c = red[tid + 128];
            float4 o = make_float4(a.x + c.x, a.y + c.y, a.z + c.z, a.w + c.w);
            ((float4*)(part + ((size_t)ch * B_ + b) * H_))[tid] = o;
        }
    }
}

// ---------------------------------------------------------------------------
// K3: finalize per sample: activations, hactiv/cell outputs, myeta, v
// ---------------------------------------------------------------------------
__global__ __launch_bounds__(256) void k_finalize(
    const float* __restrict__ pre, const float* __restrict__ part,
    const float* __restrict__ c0, const float* __restrict__ alpha,
    const float* __restrict__ Wmod, const float* __restrict__ bmod,
    const float* __restrict__ Wfan, const float* __restrict__ bfan,
    float* __restrict__ out, float* __restrict__ v) {

    int b = blockIdx.x;
    int t = threadIdx.x;

    float c2r[2];
    float local = 0.f;
    #pragma unroll
    for (int s = 0; s < 2; ++s) {
        int k = t + s * 256;
        float dot = 0.f;
        #pragma unroll
        for (int c = 0; c < NCH; ++c) dot += part[((size_t)c * B_ + b) * H_ + k];
        float pf = pre[0 * BH + (size_t)b * H_ + k];
        float pi = pre[1 * BH + (size_t)b * H_ + k];
        float po = pre[2 * BH + (size_t)b * H_ + k];
        float pc = pre[3 * BH + (size_t)b * H_ + k];
        float c2 = tanhf(pc + alpha[k] * dot);
        float fg = 1.f / (1.f + expf(-pf));
        float ig = 1.f / (1.f + expf(-pi));
        float og = 1.f / (1.f + expf(-po));
        float cell = fg * c0[(size_t)b * H_ + k] + ig * c2;
        float ha = og * tanhf(cell);
        out[(size_t)b * H_ + k] = ha;           // hactiv
        out[BH + (size_t)b * H_ + k] = cell;    // cell
        c2r[s] = c2;
        local += ha * Wmod[k];
    }
    float x = local;
    #pragma unroll
    for (int off = 32; off > 0; off >>= 1) x += __shfl_down(x, off, 64);
    __shared__ float red[4];
    int wid = t >> 6, lane = t & 63;
    if (lane == 0) red[wid] = x;
    __syncthreads();
    float s4 = red[0] + red[1] + red[2] + red[3];
    float myeta = tanhf(s4 + bmod[0]);
    #pragma unroll
    for (int s = 0; s < 2; ++s) {
        int k = t + s * 256;
        v[(size_t)b * H_ + k] = (myeta * Wfan[k] + bfan[k]) * c2r[s];
    }
}

// ---------------------------------------------------------------------------
// K4: hebb_new = clip(hebb + h0[b,h]*v[b,k], -2, 2)
// Reverse-order stream (tail of hebbdot's read freshest in L3) + NT stores.
// ---------------------------------------------------------------------------
__global__ __launch_bounds__(256) void k_update(
    const float4* __restrict__ hebb, const float* __restrict__ h0,
    const float* __restrict__ v, float* __restrict__ out) {
    const int total = B_ * H_ * (H_ / 4);   // 16,777,216 float4
    int stride = gridDim.x * blockDim.x;    // 524,288
    int base = blockIdx.x * blockDim.x + threadIdx.x;
    for (int f = total - stride + base; f >= 0; f -= stride) {
        int k4 = f & 127;           // float4 col
        int h  = (f >> 7) & 511;
        int b  = f >> 16;
        float u = h0[(b << 9) + h];
        const float4* vv4 = (const float4*)v;
        float4 vv = vv4[(b << 7) + k4];
        float4 hb = hebb[f];
        f4v r;
        r.x = fminf(fmaxf(hb.x + u * vv.x, -2.f), 2.f);
        r.y = fminf(fmaxf(hb.y + u * vv.y, -2.f), 2.f);
        r.z = fminf(fmaxf(hb.z + u * vv.z, -2.f), 2.f);
        r.w = fminf(fmaxf(hb.w + u * vv.w, -2.f), 2.f);
        __builtin_nontemporal_store(r, (f4v*)(out) + f);
    }
}

// ---------------------------------------------------------------------------
extern "C" void kernel_launch(void* const* d_in, const int* in_sizes, int n_in,
                              void* d_out, int out_size, void* d_ws, size_t ws_size,
                              hipStream_t stream) {
    const float* inputs = (const float*)d_in[0];
    const float* h0     = (const float*)d_in[1];
    const float* c0     = (const float*)d_in[2];
    const float* hebb   = (const float*)d_in[3];
    const float* w      = (const float*)d_in[4];
    const float* alpha  = (const float*)d_in[5];
    const float* Wxf = (const float*)d_in[6];  const float* bxf = (const float*)d_in[7];
    const float* Whf = (const float*)d_in[8];  const float* bhf = (const float*)d_in[9];
    const float* Wxi = (const float*)d_in[10]; const float* bxi = (const float*)d_in[11];
    const float* Whi = (const float*)d_in[12]; const float* bhi = (const float*)d_in[13];
    const float* Wxo = (const float*)d_in[14]; const float* bxo = (const float*)d_in[15];
    const float* Who = (const float*)d_in[16]; const float* bho = (const float*)d_in[17];
    const float* Wxc = (const float*)d_in[18]; const float* bxc = (const float*)d_in[19];
    const float* Wmod = (const float*)d_in[20]; const float* bmod = (const float*)d_in[21];
    const float* Wfan = (const float*)d_in[22]; const float* bfan = (const float*)d_in[23];

    float* out = (float*)d_out;
    float* ws  = (float*)d_ws;
    float* pre  = ws;                 // 4*BH
    float* part = ws + 4 * BH;        // 8*BH
    float* vbuf = ws + 12 * BH;       // BH

    k_dot_gates<<<NGEMM + B_ * NCH, 256, 0, stream>>>(
        hebb, h0, inputs,
        Wxf, bxf, Whf, bhf, Wxi, bxi, Whi, bhi,
        Wxo, bxo, Who, bho, Wxc, bxc, w, pre, part);
    k_finalize<<<B_, 256, 0, stream>>>(pre, part, c0, alpha, Wmod, bmod,
                                       Wfan, bfan, out, vbuf);
    k_update<<<2048, 256, 0, stream>>>((const float4*)hebb, h0, vbuf,
                                       out + 2 * BH);
}

// Round 6
// 171.582 us; speedup vs baseline: 1.5016x; 1.0406x over previous
//
#include <hip/hip_runtime.h>
#include <math.h>

#define B_ 256
#define I_ 512
#define H_ 512
#define BH (B_*H_)
#define NCH 8            // h-chunks for hebbdot partials
#define HCH (H_/NCH)     // 64

typedef float f4v __attribute__((ext_vector_type(4)));

// ws layout (floats):
// [0, 8*BH)        : gate pre-act partials  [ks][g][b][k]  (split-K 2)
// [8*BH, 16*BH)    : hebbdot partials [NCH][B][H]
// [16*BH, 17*BH)   : v[b,k]

// ---------------------------------------------------------------------------
// Fused: blocks [0,1024) gate GEMM (split-K x2, 32x32 tile, TK=32, dbuf),
// blocks [1024, 1024+2048) hebbdot partials (HBM-bound stream). Overlap.
// ---------------------------------------------------------------------------
#define TK 32
#define LDB 34               // padded LDS row stride (floats), 8B-aligned reads
#define TILE_F (TK*LDB)      // 1088 floats per operand buffer
#define NGEMM 1024

__global__ __launch_bounds__(256) void k_dot_gates(
    const float* __restrict__ hebb, const float* __restrict__ h0,
    const float* __restrict__ inputs,
    const float* __restrict__ Wxf, const float* __restrict__ Whf,
    const float* __restrict__ Wxi, const float* __restrict__ Whi,
    const float* __restrict__ Wxo, const float* __restrict__ Who,
    const float* __restrict__ Wxc, const float* __restrict__ w,
    float* __restrict__ pre, float* __restrict__ part) {

    __shared__ float smem[4 * TILE_F];   // 17408 B; aliased by both paths
    int bid = blockIdx.x;
    int tid = threadIdx.x;

    if (bid < NGEMM) {
        // ---------------- gate GEMM path (split-K) ----------------
        int ks = bid & 1;             // 0: inputs@Wx, 1: h0@Wh (or w)
        int m0 = ((bid >> 1) & 7) * 32;
        int n0 = (bid >> 4) * 32;     // [0,2048)
        int g  = n0 >> 9;             // 0=f,1=i,2=o,3=c
        int ko0 = n0 & 511;

        const float* Asrc = ks ? h0 : inputs;
        const float* Bsrc;
        bool wpath = false;
        if (ks == 0) {
            Bsrc = (g == 0) ? Wxf : (g == 1) ? Wxi : (g == 2) ? Wxo : Wxc;
        } else {
            if (g == 3) { Bsrc = w; wpath = true; }
            else Bsrc = (g == 0) ? Whf : (g == 1) ? Whi : Who;
        }

        int row = tid >> 3;          // 0..31  (m-row / k-row for loads)
        int c4  = tid & 7;           // float4 index along k (or n for wpath)
        int tx  = tid & 15, ty = tid >> 4;   // micro-tile coords (n, m)

        float acc[2][2] = {{0.f, 0.f}, {0.f, 0.f}};
        float4 areg, breg;

        auto LOAD = [&](int t) {
            int kb = t * TK;
            areg = *(const float4*)&Asrc[(size_t)(m0 + row) * 512 + kb + c4 * 4];
            if (wpath)
                breg = *(const float4*)&Bsrc[(size_t)(kb + row) * 512 + ko0 + c4 * 4];
            else
                breg = *(const float4*)&Bsrc[(size_t)(ko0 + row) * 512 + kb + c4 * 4];
        };
        auto STORE = [&](int pbuf) {
            float* As = smem + pbuf * 2 * TILE_F;   // [TK][LDB]  (k-major)
            float* Bs = As + TILE_F;
            #pragma unroll
            for (int j = 0; j < 4; ++j)
                As[(c4 * 4 + j) * LDB + row] = ((const float*)&areg)[j];
            if (wpath) {
                #pragma unroll
                for (int j = 0; j < 4; ++j)
                    Bs[row * LDB + c4 * 4 + j] = ((const float*)&breg)[j];
            } else {
                #pragma unroll
                for (int j = 0; j < 4; ++j)
                    Bs[(c4 * 4 + j) * LDB + row] = ((const float*)&breg)[j];
            }
        };

        LOAD(0);
        STORE(0);
        for (int t = 0; t < 16; ++t) {
            __syncthreads();
            if (t < 15) LOAD(t + 1);
            int pb = t & 1;
            const float* As = smem + pb * 2 * TILE_F;
            const float* Bs = As + TILE_F;
            #pragma unroll
            for (int kk = 0; kk < TK; ++kk) {
                float2 a2 = *(const float2*)&As[kk * LDB + ty * 2];
                float2 b2 = *(const float2*)&Bs[kk * LDB + tx * 2];
                acc[0][0] += a2.x * b2.x; acc[0][1] += a2.x * b2.y;
                acc[1][0] += a2.y * b2.x; acc[1][1] += a2.y * b2.y;
            }
            if (t < 15) STORE(pb ^ 1);
        }

        float* pb_out = pre + (size_t)(ks * 4 + g) * BH;
        #pragma unroll
        for (int i = 0; i < 2; ++i) {
            #pragma unroll
            for (int j = 0; j < 2; ++j) {
                int bnum = m0 + ty * 2 + i;
                int ko = ko0 + tx * 2 + j;
                pb_out[(size_t)bnum * H_ + ko] = acc[i][j];
            }
        }
    } else {
        // ---------------- hebbdot path ----------------
        int hbid = bid - NGEMM;
        int b  = hbid >> 3;    // consecutive blocks share b -> L2 locality
        int ch = hbid & 7;

        float*  h0s = smem;                    // [64]
        float4* red = (float4*)(smem + 64);    // [256]

        if (tid < HCH) h0s[tid] = h0[b * H_ + ch * HCH + tid];
        __syncthreads();

        const float4* hbp = (const float4*)(hebb + ((size_t)b * H_ + (size_t)ch * HCH) * H_);
        int tk = tid & 127;    // float4 column
        int th = tid >> 7;     // 0,1 — split h range
        float4 acc = make_float4(0.f, 0.f, 0.f, 0.f);
        #pragma unroll 8
        for (int r = 0; r < 32; ++r) {
            int hh = th * 32 + r;
            float s = h0s[hh];
            float4 vv = hbp[(size_t)hh * 128 + tk];
            acc.x += s * vv.x; acc.y += s * vv.y;
            acc.z += s * vv.z; acc.w += s * vv.w;
        }
        red[tid] = acc;
        __syncthreads();
        if (tid < 128) {
            float4 a = red[tid], c = red[tid + 128];
            float4 o = make_float4(a.x + c.x, a.y + c.y, a.z + c.z, a.w + c.w);
            ((float4*)(part + ((size_t)ch * B_ + b) * H_))[tid] = o;
        }
    }
}

// ---------------------------------------------------------------------------
// K3: finalize per sample: bias add, activations, outputs, myeta, v
// ---------------------------------------------------------------------------
__global__ __launch_bounds__(256) void k_finalize(
    const float* __restrict__ pre, const float* __restrict__ part,
    const float* __restrict__ c0, const float* __restrict__ alpha,
    const float* __restrict__ bxf, const float* __restrict__ bhf,
    const float* __restrict__ bxi, const float* __restrict__ bhi,
    const float* __restrict__ bxo, const float* __restrict__ bho,
    const float* __restrict__ bxc,
    const float* __restrict__ Wmod, const float* __restrict__ bmod,
    const float* __restrict__ Wfan, const float* __restrict__ bfan,
    float* __restrict__ out, float* __restrict__ v) {

    int b = blockIdx.x;
    int t = threadIdx.x;

    float c2r[2];
    float local = 0.f;
    #pragma unroll
    for (int s = 0; s < 2; ++s) {
        int k = t + s * 256;
        float dot = 0.f;
        #pragma unroll
        for (int c = 0; c < NCH; ++c) dot += part[((size_t)c * B_ + b) * H_ + k];
        size_t off = (size_t)b * H_ + k;
        float pf = pre[0 * BH + off] + pre[4 * BH + off] + bxf[k] + bhf[k];
        float pi = pre[1 * BH + off] + pre[5 * BH + off] + bxi[k] + bhi[k];
        float po = pre[2 * BH + off] + pre[6 * BH + off] + bxo[k] + bho[k];
        float pc = pre[3 * BH + off] + pre[7 * BH + off] + bxc[k];
        float c2 = tanhf(pc + alpha[k] * dot);
        float fg = 1.f / (1.f + expf(-pf));
        float ig = 1.f / (1.f + expf(-pi));
        float og = 1.f / (1.f + expf(-po));
        float cell = fg * c0[off] + ig * c2;
        float ha = og * tanhf(cell);
        out[off] = ha;                 // hactiv
        out[BH + off] = cell;          // cell
        c2r[s] = c2;
        local += ha * Wmod[k];
    }
    float x = local;
    #pragma unroll
    for (int off = 32; off > 0; off >>= 1) x += __shfl_down(x, off, 64);
    __shared__ float red[4];
    int wid = t >> 6, lane = t & 63;
    if (lane == 0) red[wid] = x;
    __syncthreads();
    float s4 = red[0] + red[1] + red[2] + red[3];
    float myeta = tanhf(s4 + bmod[0]);
    #pragma unroll
    for (int s = 0; s < 2; ++s) {
        int k = t + s * 256;
        v[(size_t)b * H_ + k] = (myeta * Wfan[k] + bfan[k]) * c2r[s];
    }
}

// ---------------------------------------------------------------------------
// K4: hebb_new = clip(hebb + h0[b,h]*v[b,k], -2, 2)
// Reverse-order stream (tail of hebbdot's read freshest in L3) + NT stores.
// ---------------------------------------------------------------------------
__global__ __launch_bounds__(256) void k_update(
    const float4* __restrict__ hebb, const float* __restrict__ h0,
    const float* __restrict__ v, float* __restrict__ out) {
    const int total = B_ * H_ * (H_ / 4);   // 16,777,216 float4
    int stride = gridDim.x * blockDim.x;    // 524,288
    int base = blockIdx.x * blockDim.x + threadIdx.x;
    for (int f = total - stride + base; f >= 0; f -= stride) {
        int k4 = f & 127;           // float4 col
        int h  = (f >> 7) & 511;
        int b  = f >> 16;
        float u = h0[(b << 9) + h];
        const float4* vv4 = (const float4*)v;
        float4 vv = vv4[(b << 7) + k4];
        float4 hb = hebb[f];
        f4v r;
        r.x = fminf(fmaxf(hb.x + u * vv.x, -2.f), 2.f);
        r.y = fminf(fmaxf(hb.y + u * vv.y, -2.f), 2.f);
        r.z = fminf(fmaxf(hb.z + u * vv.z, -2.f), 2.f);
        r.w = fminf(fmaxf(hb.w + u * vv.w, -2.f), 2.f);
        __builtin_nontemporal_store(r, (f4v*)(out) + f);
    }
}

// ---------------------------------------------------------------------------
extern "C" void kernel_launch(void* const* d_in, const int* in_sizes, int n_in,
                              void* d_out, int out_size, void* d_ws, size_t ws_size,
                              hipStream_t stream) {
    const float* inputs = (const float*)d_in[0];
    const float* h0     = (const float*)d_in[1];
    const float* c0     = (const float*)d_in[2];
    const float* hebb   = (const float*)d_in[3];
    const float* w      = (const float*)d_in[4];
    const float* alpha  = (const float*)d_in[5];
    const float* Wxf = (const float*)d_in[6];  const float* bxf = (const float*)d_in[7];
    const float* Whf = (const float*)d_in[8];  const float* bhf = (const float*)d_in[9];
    const float* Wxi = (const float*)d_in[10]; const float* bxi = (const float*)d_in[11];
    const float* Whi = (const float*)d_in[12]; const float* bhi = (const float*)d_in[13];
    const float* Wxo = (const float*)d_in[14]; const float* bxo = (const float*)d_in[15];
    const float* Who = (const float*)d_in[16]; const float* bho = (const float*)d_in[17];
    const float* Wxc = (const float*)d_in[18]; const float* bxc = (const float*)d_in[19];
    const float* Wmod = (const float*)d_in[20]; const float* bmod = (const float*)d_in[21];
    const float* Wfan = (const float*)d_in[22]; const float* bfan = (const float*)d_in[23];

    float* out = (float*)d_out;
    float* ws  = (float*)d_ws;
    float* pre  = ws;                  // 8*BH (split-K partials)
    float* part = ws + 8 * BH;         // 8*BH
    float* vbuf = ws + 16 * BH;        // BH

    k_dot_gates<<<NGEMM + B_ * NCH, 256, 0, stream>>>(
        hebb, h0, inputs,
        Wxf, Whf, Wxi, Whi, Wxo, Who, Wxc, w, pre, part);
    k_finalize<<<B_, 256, 0, stream>>>(pre, part, c0, alpha,
                                       bxf, bhf, bxi, bhi, bxo, bho, bxc,
                                       Wmod, bmod, Wfan, bfan, out, vbuf);
    k_update<<<2048, 256, 0, stream>>>((const float4*)hebb, h0, vbuf,
                                       out + 2 * BH);
}